// Round 9
// baseline (534.822 us; speedup 1.0000x reference)
//
#include <hip/hip_runtime.h>
#include <cstdint>
#include <cstddef>

// Problem constants
#define B_N   16384
#define D_DIM 16
#define K_NBR 25
#define CAP   384       // per-row LDS candidate capacity (E[C]~208, sigma~57)
#define MAXL  6         // CAP/64
#define NSAMP 1024      // threshold sample count per row

// Workspace: accum 256B | sq 64KB | T 64KB | rawh 512KB | rawl 512KB
#define WS_SQ_OFF   256
#define WS_T_OFF    (WS_SQ_OFF + 65536)
#define WS_RAWH_OFF (WS_T_OFF + 65536)
#define WS_RAWL_OFF (WS_RAWH_OFF + B_N * D_DIM * 2)

typedef __attribute__((ext_vector_type(8))) short bf16x8;
typedef __attribute__((ext_vector_type(4))) float f32x4;

__device__ __forceinline__ unsigned map_f32(float x) {
    unsigned u = __float_as_uint(x);
    return (u & 0x80000000u) ? ~u : (u | 0x80000000u); // order-preserving
}

__device__ __forceinline__ unsigned short f2bf(float x) {   // RNE f32->bf16 bits
    unsigned u = __float_as_uint(x);
    unsigned r = (u + 0x7FFFu + ((u >> 16) & 1u)) >> 16;
    return (unsigned short)r;
}
__device__ __forceinline__ float bf2f(unsigned short h) {
    return __uint_as_float(((unsigned)h) << 16);
}

// ---------------------------------------------------------------- prep: sq + recon MSE + bf16 hi/lo split
__global__ __launch_bounds__(256) void prep_kernel(const float4* __restrict__ rawv,
                                                   const float4* __restrict__ ov,
                                                   const float4* __restrict__ tv,
                                                   float* __restrict__ sq,
                                                   unsigned short* __restrict__ rawh,
                                                   unsigned short* __restrict__ rawl,
                                                   float* __restrict__ accum) {
    int i = blockIdx.x * 256 + threadIdx.x;
    float v[16];
    {
        float4 r0 = rawv[i*4+0], r1 = rawv[i*4+1], r2 = rawv[i*4+2], r3 = rawv[i*4+3];
        v[0]=r0.x; v[1]=r0.y; v[2]=r0.z; v[3]=r0.w;
        v[4]=r1.x; v[5]=r1.y; v[6]=r1.z; v[7]=r1.w;
        v[8]=r2.x; v[9]=r2.y; v[10]=r2.z; v[11]=r2.w;
        v[12]=r3.x; v[13]=r3.y; v[14]=r3.z; v[15]=r3.w;
    }
    float s = 0.0f;
    unsigned short h[16], l[16];
    #pragma unroll
    for (int k = 0; k < 16; ++k) {
        s = fmaf(v[k], v[k], s);
        unsigned short hh = f2bf(v[k]);
        h[k] = hh;
        l[k] = f2bf(v[k] - bf2f(hh));
    }
    sq[i] = s;
    #pragma unroll
    for (int q = 0; q < 4; ++q) {
        ((ushort4*)(rawh + (size_t)i*16))[q] = make_ushort4(h[q*4], h[q*4+1], h[q*4+2], h[q*4+3]);
        ((ushort4*)(rawl + (size_t)i*16))[q] = make_ushort4(l[q*4], l[q*4+1], l[q*4+2], l[q*4+3]);
    }

    float rs = 0.0f;
    #pragma unroll
    for (int q = 0; q < 4; ++q) {
        float4 o = ov[i*4+q], t = tv[i*4+q];
        float d;
        d = o.x - t.x; rs = fmaf(d, d, rs);
        d = o.y - t.y; rs = fmaf(d, d, rs);
        d = o.z - t.z; rs = fmaf(d, d, rs);
        d = o.w - t.w; rs = fmaf(d, d, rs);
    }
    #pragma unroll
    for (int off = 32; off >= 1; off >>= 1) rs += __shfl_down(rs, off, 64);
    if ((threadIdx.x & 63) == 0) atomicAdd(&accum[0], rs);
}

// ---------------------------------------------------------------- per-row distance threshold, LDS-staged
__global__ __launch_bounds__(256) void thresh_kernel(const float4* __restrict__ rawv,
                                                     const unsigned short* __restrict__ rawh,
                                                     const float* __restrict__ sq,
                                                     float* __restrict__ T) {
    __shared__ unsigned short sampH[NSAMP * 16];  // 32 KB
    __shared__ float sampSq[NSAMP];               // 4 KB
    __shared__ float V[16][48];                   // 3 KB

    int tid = threadIdx.x;
    for (int s = tid; s < NSAMP; s += 256) {
        int js = s << 4;
        const uint4* src = (const uint4*)(rawh + (size_t)js * 16);
        ((uint4*)(sampH + s * 16))[0] = src[0];
        ((uint4*)(sampH + s * 16))[1] = src[1];
        sampSq[s] = sq[js];
    }

    int rl   = tid >> 4;
    int sidx = tid & 15;
    int i = blockIdx.x * 16 + rl;

    float a[16];
    {
        float4 r0 = rawv[i*4+0], r1 = rawv[i*4+1], r2 = rawv[i*4+2], r3 = rawv[i*4+3];
        a[0]=r0.x; a[1]=r0.y; a[2]=r0.z; a[3]=r0.w;
        a[4]=r1.x; a[5]=r1.y; a[6]=r1.z; a[7]=r1.w;
        a[8]=r2.x; a[9]=r2.y; a[10]=r2.z; a[11]=r2.w;
        a[12]=r3.x; a[13]=r3.y; a[14]=r3.z; a[15]=r3.w;
    }
    float sqi = sq[i];
    __syncthreads();

    float s0 = 3e37f, s1 = 3e37f, s2 = 3e37f;
    for (int t = 0; t < NSAMP / 16; ++t) {
        int s = t * 16 + sidx;      // interleaved: consecutive lanes -> consecutive rows
        const uint4* bp = (const uint4*)(sampH + s * 16);
        uint4 h0 = bp[0], h1 = bp[1];
        float dot = 0.0f;
        unsigned w;
        w = h0.x; dot = fmaf(a[0],  __uint_as_float(w << 16), dot); dot = fmaf(a[1],  __uint_as_float(w & 0xFFFF0000u), dot);
        w = h0.y; dot = fmaf(a[2],  __uint_as_float(w << 16), dot); dot = fmaf(a[3],  __uint_as_float(w & 0xFFFF0000u), dot);
        w = h0.z; dot = fmaf(a[4],  __uint_as_float(w << 16), dot); dot = fmaf(a[5],  __uint_as_float(w & 0xFFFF0000u), dot);
        w = h0.w; dot = fmaf(a[6],  __uint_as_float(w << 16), dot); dot = fmaf(a[7],  __uint_as_float(w & 0xFFFF0000u), dot);
        w = h1.x; dot = fmaf(a[8],  __uint_as_float(w << 16), dot); dot = fmaf(a[9],  __uint_as_float(w & 0xFFFF0000u), dot);
        w = h1.y; dot = fmaf(a[10], __uint_as_float(w << 16), dot); dot = fmaf(a[11], __uint_as_float(w & 0xFFFF0000u), dot);
        w = h1.z; dot = fmaf(a[12], __uint_as_float(w << 16), dot); dot = fmaf(a[13], __uint_as_float(w & 0xFFFF0000u), dot);
        w = h1.w; dot = fmaf(a[14], __uint_as_float(w << 16), dot); dot = fmaf(a[15], __uint_as_float(w & 0xFFFF0000u), dot);
        float cur = sqi + sampSq[s] - 2.0f * dot;
        float lo;
        lo = fminf(s0, cur); cur = fmaxf(s0, cur); s0 = lo;
        lo = fminf(s1, cur); cur = fmaxf(s1, cur); s1 = lo;
        lo = fminf(s2, cur); cur = fmaxf(s2, cur); s2 = lo;
    }

    V[rl][sidx*3+0] = s0; V[rl][sidx*3+1] = s1; V[rl][sidx*3+2] = s2;
    __syncthreads();

    int cl0 = 0, cq0 = 0, cl1 = 0, cq1 = 0, cl2 = 0, cq2 = 0;
    for (int k = 0; k < 48; ++k) {
        float v = V[rl][k];
        cl0 += (v < s0); cq0 += (v <= s0);
        cl1 += (v < s1); cq1 += (v <= s1);
        cl2 += (v < s2); cq2 += (v <= s2);
    }
    if (cl0 <= 12 && 12 < cq0) T[i] = s0 + 0.05f;
    else if (cl1 <= 12 && 12 < cq1) T[i] = s1 + 0.05f;
    else if (cl2 <= 12 && 12 < cq2) T[i] = s2 + 0.05f;
}

// ---------------------------------------------------------------- fused MFMA scan + select + eig + dot
// NOTE: plain __launch_bounds__(256). On gfx950 the VGPR/AGPR file is unified;
// __launch_bounds__(256,4) capped total regs at ~128 -> 64 VGPR + AGPR split ->
// eig arrays spilled (183 MB scratch writes, R7/R8). Plain (256) gave VGPR=100,
// no spill (R6). Do not re-add the second argument.
__global__ __launch_bounds__(256) void tsa_kernel(const unsigned short* __restrict__ rawh,
                                                  const unsigned short* __restrict__ rawl,
                                                  const float4* __restrict__ latv,
                                                  const float4* __restrict__ rawv,
                                                  const float* __restrict__ sq,
                                                  const float* __restrict__ T,
                                                  float* __restrict__ accum) {
    __shared__ unsigned keyS[16 * CAP];   // 24 KB; aliased as ZS/XS in phase 2b
    __shared__ int      cntS[16];
    __shared__ int      nbrAll[16][K_NBR];
    __shared__ int      gotS[16];

    int tid  = threadIdx.x;
    int wave = tid >> 6;
    int lane = tid & 63;
    int quad = lane >> 4;
    int lnib = lane & 15;
    int i0   = blockIdx.x * 16;
    int koff = (quad & 1) * 8;

    if (tid < 16) cntS[tid] = 0;

    // A-frag: 16x16x32 layout A[m=lane&15][k=quad*8+jj]; k<16 = ah, k>=16 = al
    const unsigned short* abase = (quad < 2 ? rawh : rawl) + (size_t)(i0 + lnib) * 16 + koff;
    bf16x8 afrag = *(const bf16x8*)abase;

    float sqi[4], hcut[4];
    #pragma unroll
    for (int r = 0; r < 4; ++r) {
        int m = quad * 4 + r;
        sqi[r]  = sq[i0 + m];
        hcut[r] = 0.5f * (sqi[r] - T[i0 + m]);   // cond: acc > 0.5*sqj + hcut  <=>  d2 < T
    }

    __syncthreads();

    // ---- phase 1: MFMA distance scan, 2 tiles per iteration for ILP
    for (int t = wave; t < B_N / 16; t += 8) {
        int tB = t + 4;
        int jA = t  * 16 + lnib;
        int jB = tB * 16 + lnib;
        bf16x8 bhA = *(const bf16x8*)(rawh + (size_t)jA * 16 + koff);
        bf16x8 blA = *(const bf16x8*)(rawl + (size_t)jA * 16 + koff);
        bf16x8 bhB = *(const bf16x8*)(rawh + (size_t)jB * 16 + koff);
        bf16x8 blB = *(const bf16x8*)(rawl + (size_t)jB * 16 + koff);
        float sqjA = sq[jA];
        float sqjB = sq[jB];
        f32x4 accA = {0.f, 0.f, 0.f, 0.f};
        f32x4 accB = {0.f, 0.f, 0.f, 0.f};
        accA = __builtin_amdgcn_mfma_f32_16x16x32_bf16(afrag, blA, accA, 0, 0, 0);
        accB = __builtin_amdgcn_mfma_f32_16x16x32_bf16(afrag, blB, accB, 0, 0, 0);
        accA = __builtin_amdgcn_mfma_f32_16x16x32_bf16(afrag, bhA, accA, 0, 0, 0);
        accB = __builtin_amdgcn_mfma_f32_16x16x32_bf16(afrag, bhB, accB, 0, 0, 0);
        // C/D layout: col=lane&15 (j), row=quad*4+reg (i)
        #pragma unroll
        for (int r = 0; r < 4; ++r) {
            int m = quad * 4 + r;
            if ((accA[r] > fmaf(0.5f, sqjA, hcut[r])) && (jA != i0 + m)) {
                float d2 = sqi[r] + sqjA - 2.0f * accA[r];
                int pos = atomicAdd(&cntS[m], 1);
                if (pos < CAP) keyS[m * CAP + pos] = (map_f32(d2) & 0xFFFF0000u) | (unsigned)jA;
            }
        }
        #pragma unroll
        for (int r = 0; r < 4; ++r) {
            int m = quad * 4 + r;
            if ((accB[r] > fmaf(0.5f, sqjB, hcut[r])) && (jB != i0 + m)) {
                float d2 = sqi[r] + sqjB - 2.0f * accB[r];
                int pos = atomicAdd(&cntS[m], 1);
                if (pos < CAP) keyS[m * CAP + pos] = (map_f32(d2) & 0xFFFF0000u) | (unsigned)jB;
            }
        }
    }
    __syncthreads();

    // ---- phase 2a: per wave, 4 bisections + ballot-prefix collect (no atomics, no barriers)
    unsigned long long ltm = (1ull << lane) - 1ull;
    for (int rr = 0; rr < 4; ++rr) {
        int m = wave * 4 + rr;
        int C = cntS[m]; C = C < CAP ? C : CAP;
        unsigned kl[MAXL];
        #pragma unroll
        for (int tt = 0; tt < MAXL; ++tt) {
            int c = tt * 64 + lane;
            kl[tt] = (c < C) ? keyS[m * CAP + c] : 0xFFFFFFFFu;
        }
        unsigned lo = 0, hi = 0xFFFFFFFEu;
        for (int it = 0; it < 32 && lo < hi; ++it) {
            unsigned mid = lo + ((hi - lo) >> 1);
            unsigned cc = 0;
            #pragma unroll
            for (int tt = 0; tt < MAXL; ++tt)
                cc += (unsigned)__builtin_popcountll(__ballot(kl[tt] <= mid));
            if (cc >= K_NBR) hi = mid; else lo = mid + 1;
        }
        unsigned T25 = hi;

        int base = 0;
        #pragma unroll
        for (int tt = 0; tt < MAXL; ++tt) {
            bool c = kl[tt] <= T25;
            unsigned long long mk = __ballot(c);
            if (c) {
                int pos = base + __builtin_popcountll(mk & ltm);
                if (pos < K_NBR) nbrAll[m][pos] = (int)(kl[tt] & 0xFFFFu);
            }
            base += __builtin_popcountll(mk);
        }
        if (lane == 0) gotS[m] = base < K_NBR ? base : K_NBR;
    }
    __syncthreads();   // all keyS reads done -> safe to alias

    // ---- phase 2b: eig per wave (ZS/XS carved out of keyS region)
    float* ZS = (float*)keyS + wave * 800;   // 400 floats Z + 400 floats X
    float* XS = ZS + 400;

    for (int rr = 0; rr < 4; ++rr) {
        int m  = wave * 4 + rr;
        int pt = i0 + m;

        if (lane < K_NBR) {
            int got = gotS[m];
            int n = (lane < got) ? nbrAll[m][lane] : ((got > 0) ? nbrAll[m][0] : pt);
            float4* z = (float4*)&ZS[lane * D_DIM];
            float4* x = (float4*)&XS[lane * D_DIM];
            z[0] = latv[n*4+0]; z[1] = latv[n*4+1]; z[2] = latv[n*4+2]; z[3] = latv[n*4+3];
            x[0] = rawv[n*4+0]; x[1] = rawv[n*4+1]; x[2] = rawv[n*4+2]; x[3] = rawv[n*4+3];
        }
        __syncthreads();

        // 4 groups of 16 lanes: (Z,X) x (half0, half1)
        int a     = lane & 15;
        int com   = lane & 16;
        int hb    = lane >> 5;
        int sbase = lane & 48;
        float* M = com ? XS : ZS;

        int k0 = hb ? 13 : 0;
        int k1 = hb ? 25 : 13;
        {
            float s = 0.0f;
            for (int k = k0; k < k1; ++k) s += M[k * D_DIM + a];
            s += __shfl_xor(s, 32, 64);
            float mean = s * 0.04f;
            for (int k = k0; k < k1; ++k) M[k * D_DIM + a] -= mean;
        }
        __syncthreads();

        float row[16];
        #pragma unroll
        for (int b = 0; b < 16; ++b) row[b] = 0.0f;
        for (int k = k0; k < k1; ++k) {
            float va = M[k * D_DIM + a];
            #pragma unroll
            for (int b = 0; b < 16; ++b) row[b] = fmaf(va, M[k * D_DIM + b], row[b]);
        }
        #pragma unroll
        for (int b = 0; b < 16; ++b) row[b] += __shfl_xor(row[b], 32, 64);

        float mm = 1e-30f;
        #pragma unroll
        for (int b = 0; b < 16; ++b) mm = fmaxf(mm, fabsf(row[b]));
        #pragma unroll
        for (int off = 1; off < 16; off <<= 1) mm = fmaxf(mm, __shfl_xor(mm, off, 64));
        float inv = 1.0f / mm;
        #pragma unroll
        for (int b = 0; b < 16; ++b) row[b] *= inv;

        int bbase = sbase + (hb << 3);

        for (int sq3 = 0; sq3 < 3; ++sq3) {   // net C^8
            float rh[8];
            #pragma unroll
            for (int bi = 0; bi < 8; ++bi) rh[bi] = hb ? row[8 + bi] : row[bi];
            float nr[16];
            #pragma unroll
            for (int c = 0; c < 16; ++c) nr[c] = 0.0f;
            #pragma unroll
            for (int bi = 0; bi < 8; ++bi) {
                float coef = rh[bi];
                #pragma unroll
                for (int c = 0; c < 16; ++c)
                    nr[c] = fmaf(coef, __shfl(row[c], bbase + bi, 64), nr[c]);
            }
            #pragma unroll
            for (int c = 0; c < 16; ++c) nr[c] += __shfl_xor(nr[c], 32, 64);
            mm = 1e-30f;
            #pragma unroll
            for (int c = 0; c < 16; ++c) mm = fmaxf(mm, fabsf(nr[c]));
            #pragma unroll
            for (int off = 1; off < 16; off <<= 1) mm = fmaxf(mm, __shfl_xor(mm, off, 64));
            inv = 1.0f / mm;
            #pragma unroll
            for (int c = 0; c < 16; ++c) row[c] = nr[c] * inv;
        }

        float rh[8];
        #pragma unroll
        for (int bi = 0; bi < 8; ++bi) rh[bi] = hb ? row[8 + bi] : row[bi];
        float v = 1.0f + 0.0625f * (float)a;
        for (int it = 0; it < 16; ++it) {     // ~C^128 effective
            float w = 0.0f;
            #pragma unroll
            for (int bi = 0; bi < 8; ++bi)
                w = fmaf(rh[bi], __shfl(v, bbase + bi, 64), w);
            w += __shfl_xor(w, 32, 64);
            float n2 = w * w;
            #pragma unroll
            for (int off = 1; off < 16; off <<= 1) n2 += __shfl_xor(n2, off, 64);
            v = w * rsqrtf(n2 + 1e-37f);
        }
        {
            float n2 = v * v;
            #pragma unroll
            for (int off = 1; off < 16; off <<= 1) n2 += __shfl_xor(n2, off, 64);
            v = v / sqrtf(n2 + 1e-37f);
        }

        float p = v * __shfl_xor(v, 16, 64);
        #pragma unroll
        for (int off = 1; off < 16; off <<= 1) p += __shfl_xor(p, off, 64);
        if (lane == 0) atomicAdd(&accum[1], p * p);
        __syncthreads();
    }
}

// ---------------------------------------------------------------- combine
__global__ void final_kernel(const float* __restrict__ accum, float* __restrict__ out) {
    float recon = accum[0] * (1.0f / (float)(B_N * D_DIM));
    float tsa   = 2.0f - 2.0f * (accum[1] * (1.0f / (float)B_N));
    out[0] = recon + 0.1f * tsa;
}

extern "C" void kernel_launch(void* const* d_in, const int* in_sizes, int n_in,
                              void* d_out, int out_size, void* d_ws, size_t ws_size,
                              hipStream_t stream) {
    const float* outputs = (const float*)d_in[0];
    const float* targets = (const float*)d_in[1];
    const float* latent  = (const float*)d_in[2];
    const float* raw     = (const float*)d_in[3];

    float* accum         = (float*)d_ws;
    float* sq            = (float*)((char*)d_ws + WS_SQ_OFF);
    float* T             = (float*)((char*)d_ws + WS_T_OFF);
    unsigned short* rawh = (unsigned short*)((char*)d_ws + WS_RAWH_OFF);
    unsigned short* rawl = (unsigned short*)((char*)d_ws + WS_RAWL_OFF);

    const float4* rawv = (const float4*)raw;
    const float4* latv = (const float4*)latent;

    hipMemsetAsync(d_ws, 0, 256, stream);  // zero accum
    prep_kernel<<<B_N / 256, 256, 0, stream>>>(rawv, (const float4*)outputs,
                                               (const float4*)targets, sq, rawh, rawl, accum);
    thresh_kernel<<<B_N / 16, 256, 0, stream>>>(rawv, rawh, sq, T);
    tsa_kernel<<<B_N / 16, 256, 0, stream>>>(rawh, rawl, latv, rawv, sq, T, accum);
    final_kernel<<<1, 1, 0, stream>>>(accum, (float*)d_out);
}

// Round 10
// 438.914 us; speedup vs baseline: 1.2185x; 1.2185x over previous
//
#include <hip/hip_runtime.h>
#include <cstdint>
#include <cstddef>

// Problem constants
#define B_N   16384
#define D_DIM 16
#define K_NBR 25
#define CAP   256       // per-row LDS candidate capacity (E[C]~96, P(>256)~1e-3 benign)
#define MAXL  4         // CAP/64
#define NSAMP 1024      // threshold sample count per row

// Workspace: accum 256B | sq 64KB | T 64KB | rawh 512KB | rawl 512KB | nbrG 1.6MB
#define WS_SQ_OFF   256
#define WS_T_OFF    (WS_SQ_OFF + 65536)
#define WS_RAWH_OFF (WS_T_OFF + 65536)
#define WS_RAWL_OFF (WS_RAWH_OFF + B_N * D_DIM * 2)
#define WS_NBR_OFF  (WS_RAWL_OFF + B_N * D_DIM * 2)

typedef __attribute__((ext_vector_type(8))) short bf16x8;
typedef __attribute__((ext_vector_type(4))) float f32x4;

__device__ __forceinline__ unsigned map_f32(float x) {
    unsigned u = __float_as_uint(x);
    return (u & 0x80000000u) ? ~u : (u | 0x80000000u); // order-preserving
}

__device__ __forceinline__ unsigned short f2bf(float x) {   // RNE f32->bf16 bits
    unsigned u = __float_as_uint(x);
    unsigned r = (u + 0x7FFFu + ((u >> 16) & 1u)) >> 16;
    return (unsigned short)r;
}
__device__ __forceinline__ float bf2f(unsigned short h) {
    return __uint_as_float(((unsigned)h) << 16);
}

// ---------------------------------------------------------------- prep: sq + recon MSE + bf16 hi/lo split
__global__ __launch_bounds__(256) void prep_kernel(const float4* __restrict__ rawv,
                                                   const float4* __restrict__ ov,
                                                   const float4* __restrict__ tv,
                                                   float* __restrict__ sq,
                                                   unsigned short* __restrict__ rawh,
                                                   unsigned short* __restrict__ rawl,
                                                   float* __restrict__ accum) {
    int i = blockIdx.x * 256 + threadIdx.x;
    float v[16];
    {
        float4 r0 = rawv[i*4+0], r1 = rawv[i*4+1], r2 = rawv[i*4+2], r3 = rawv[i*4+3];
        v[0]=r0.x; v[1]=r0.y; v[2]=r0.z; v[3]=r0.w;
        v[4]=r1.x; v[5]=r1.y; v[6]=r1.z; v[7]=r1.w;
        v[8]=r2.x; v[9]=r2.y; v[10]=r2.z; v[11]=r2.w;
        v[12]=r3.x; v[13]=r3.y; v[14]=r3.z; v[15]=r3.w;
    }
    float s = 0.0f;
    unsigned short h[16], l[16];
    #pragma unroll
    for (int k = 0; k < 16; ++k) {
        s = fmaf(v[k], v[k], s);
        unsigned short hh = f2bf(v[k]);
        h[k] = hh;
        l[k] = f2bf(v[k] - bf2f(hh));
    }
    sq[i] = s;
    #pragma unroll
    for (int q = 0; q < 4; ++q) {
        ((ushort4*)(rawh + (size_t)i*16))[q] = make_ushort4(h[q*4], h[q*4+1], h[q*4+2], h[q*4+3]);
        ((ushort4*)(rawl + (size_t)i*16))[q] = make_ushort4(l[q*4], l[q*4+1], l[q*4+2], l[q*4+3]);
    }

    float rs = 0.0f;
    #pragma unroll
    for (int q = 0; q < 4; ++q) {
        float4 o = ov[i*4+q], t = tv[i*4+q];
        float d;
        d = o.x - t.x; rs = fmaf(d, d, rs);
        d = o.y - t.y; rs = fmaf(d, d, rs);
        d = o.z - t.z; rs = fmaf(d, d, rs);
        d = o.w - t.w; rs = fmaf(d, d, rs);
    }
    #pragma unroll
    for (int off = 32; off >= 1; off >>= 1) rs += __shfl_down(rs, off, 64);
    if ((threadIdx.x & 63) == 0) atomicAdd(&accum[0], rs);
}

// ---------------------------------------------------------------- per-row distance threshold, LDS-staged
// T[i] = 6th smallest of 48 per-thread partials (>= true 6th of 1024 samples -> errs safe/larger).
// E[full count below T] ~ 96; P(<25) ~ 0.5% (padded downstream, bounded impact).
__global__ __launch_bounds__(256) void thresh_kernel(const float4* __restrict__ rawv,
                                                     const unsigned short* __restrict__ rawh,
                                                     const float* __restrict__ sq,
                                                     float* __restrict__ T) {
    __shared__ unsigned short sampH[NSAMP * 16];  // 32 KB
    __shared__ float sampSq[NSAMP];               // 4 KB
    __shared__ float V[16][48];                   // 3 KB

    int tid = threadIdx.x;
    for (int s = tid; s < NSAMP; s += 256) {
        int js = s << 4;
        const uint4* src = (const uint4*)(rawh + (size_t)js * 16);
        ((uint4*)(sampH + s * 16))[0] = src[0];
        ((uint4*)(sampH + s * 16))[1] = src[1];
        sampSq[s] = sq[js];
    }

    int rl   = tid >> 4;
    int sidx = tid & 15;
    int i = blockIdx.x * 16 + rl;

    float a[16];
    {
        float4 r0 = rawv[i*4+0], r1 = rawv[i*4+1], r2 = rawv[i*4+2], r3 = rawv[i*4+3];
        a[0]=r0.x; a[1]=r0.y; a[2]=r0.z; a[3]=r0.w;
        a[4]=r1.x; a[5]=r1.y; a[6]=r1.z; a[7]=r1.w;
        a[8]=r2.x; a[9]=r2.y; a[10]=r2.z; a[11]=r2.w;
        a[12]=r3.x; a[13]=r3.y; a[14]=r3.z; a[15]=r3.w;
    }
    float sqi = sq[i];
    __syncthreads();

    float s0 = 3e37f, s1 = 3e37f, s2 = 3e37f;
    for (int t = 0; t < NSAMP / 16; ++t) {
        int s = t * 16 + sidx;
        const uint4* bp = (const uint4*)(sampH + s * 16);
        uint4 h0 = bp[0], h1 = bp[1];
        float dot = 0.0f;
        unsigned w;
        w = h0.x; dot = fmaf(a[0],  __uint_as_float(w << 16), dot); dot = fmaf(a[1],  __uint_as_float(w & 0xFFFF0000u), dot);
        w = h0.y; dot = fmaf(a[2],  __uint_as_float(w << 16), dot); dot = fmaf(a[3],  __uint_as_float(w & 0xFFFF0000u), dot);
        w = h0.z; dot = fmaf(a[4],  __uint_as_float(w << 16), dot); dot = fmaf(a[5],  __uint_as_float(w & 0xFFFF0000u), dot);
        w = h0.w; dot = fmaf(a[6],  __uint_as_float(w << 16), dot); dot = fmaf(a[7],  __uint_as_float(w & 0xFFFF0000u), dot);
        w = h1.x; dot = fmaf(a[8],  __uint_as_float(w << 16), dot); dot = fmaf(a[9],  __uint_as_float(w & 0xFFFF0000u), dot);
        w = h1.y; dot = fmaf(a[10], __uint_as_float(w << 16), dot); dot = fmaf(a[11], __uint_as_float(w & 0xFFFF0000u), dot);
        w = h1.z; dot = fmaf(a[12], __uint_as_float(w << 16), dot); dot = fmaf(a[13], __uint_as_float(w & 0xFFFF0000u), dot);
        w = h1.w; dot = fmaf(a[14], __uint_as_float(w << 16), dot); dot = fmaf(a[15], __uint_as_float(w & 0xFFFF0000u), dot);
        float cur = sqi + sampSq[s] - 2.0f * dot;
        float lo;
        lo = fminf(s0, cur); cur = fmaxf(s0, cur); s0 = lo;
        lo = fminf(s1, cur); cur = fmaxf(s1, cur); s1 = lo;
        lo = fminf(s2, cur); cur = fmaxf(s2, cur); s2 = lo;
    }

    V[rl][sidx*3+0] = s0; V[rl][sidx*3+1] = s1; V[rl][sidx*3+2] = s2;
    __syncthreads();

    int cl0 = 0, cq0 = 0, cl1 = 0, cq1 = 0, cl2 = 0, cq2 = 0;
    for (int k = 0; k < 48; ++k) {
        float v = V[rl][k];
        cl0 += (v < s0); cq0 += (v <= s0);
        cl1 += (v < s1); cq1 += (v <= s1);
        cl2 += (v < s2); cq2 += (v <= s2);
    }
    if (cl0 <= 5 && 5 < cq0) T[i] = s0 + 0.05f;
    else if (cl1 <= 5 && 5 < cq1) T[i] = s1 + 0.05f;
    else if (cl2 <= 5 && 5 < cq2) T[i] = s2 + 0.05f;
}

// ---------------------------------------------------------------- MFMA scan + select: 32 rows/block, 512 thr
// NOTE: plain __launch_bounds__ only — (256,4) caused a 64-VGPR cap + unified-AGPR split and
// massive scratch spill on gfx950 (R7/R8, 183 MB writes). Do not add the second argument.
__global__ __launch_bounds__(512) void scan_kernel(const unsigned short* __restrict__ rawh,
                                                   const unsigned short* __restrict__ rawl,
                                                   const float* __restrict__ sq,
                                                   const float* __restrict__ T,
                                                   unsigned* __restrict__ nbrG) {
    __shared__ unsigned keyS[32 * CAP];   // 32 KB
    __shared__ int      cntS[32];
    __shared__ int      nbrW[32][K_NBR];

    int tid  = threadIdx.x;
    int wave = tid >> 6;       // 0..7
    int lane = tid & 63;
    int quad = lane >> 4;
    int lnib = lane & 15;
    int i0   = blockIdx.x * 32;
    int koff = (quad & 1) * 8;

    if (tid < 32) cntS[tid] = 0;

    // Two A-frags: rows i0..i0+15 and i0+16..i0+31 (16x16x32: A[m=lane&15][k=quad*8+jj])
    const unsigned short* ab = (quad < 2 ? rawh : rawl) + (size_t)(i0 + lnib) * 16 + koff;
    bf16x8 afrag0 = *(const bf16x8*)ab;
    bf16x8 afrag1 = *(const bf16x8*)(ab + 16 * 16);

    float sqi[8], hcut[8];
    #pragma unroll
    for (int r = 0; r < 4; ++r) {
        int m = quad * 4 + r;
        sqi[r]     = sq[i0 + m];
        hcut[r]    = 0.5f * (sqi[r] - T[i0 + m]);       // acc > 0.5*sqj + hcut  <=>  d2 < T
        sqi[4+r]   = sq[i0 + m + 16];
        hcut[4+r]  = 0.5f * (sqi[4+r] - T[i0 + m + 16]);
    }
    __syncthreads();

    // ---- phase 1: 1024 j-tiles, 8 waves, 2-tile ILP; B-frags shared by both A-frags
    for (int t = wave; t < B_N / 16; t += 16) {
        int jA = t * 16 + lnib;
        int jB = jA + 128;            // tile t+8
        bf16x8 bhA = *(const bf16x8*)(rawh + (size_t)jA * 16 + koff);
        bf16x8 blA = *(const bf16x8*)(rawl + (size_t)jA * 16 + koff);
        bf16x8 bhB = *(const bf16x8*)(rawh + (size_t)jB * 16 + koff);
        bf16x8 blB = *(const bf16x8*)(rawl + (size_t)jB * 16 + koff);
        float sqjA = sq[jA];
        float sqjB = sq[jB];
        f32x4 a0A = {0,0,0,0}, a1A = {0,0,0,0}, a0B = {0,0,0,0}, a1B = {0,0,0,0};
        a0A = __builtin_amdgcn_mfma_f32_16x16x32_bf16(afrag0, blA, a0A, 0, 0, 0);
        a1A = __builtin_amdgcn_mfma_f32_16x16x32_bf16(afrag1, blA, a1A, 0, 0, 0);
        a0B = __builtin_amdgcn_mfma_f32_16x16x32_bf16(afrag0, blB, a0B, 0, 0, 0);
        a1B = __builtin_amdgcn_mfma_f32_16x16x32_bf16(afrag1, blB, a1B, 0, 0, 0);
        a0A = __builtin_amdgcn_mfma_f32_16x16x32_bf16(afrag0, bhA, a0A, 0, 0, 0);
        a1A = __builtin_amdgcn_mfma_f32_16x16x32_bf16(afrag1, bhA, a1A, 0, 0, 0);
        a0B = __builtin_amdgcn_mfma_f32_16x16x32_bf16(afrag0, bhB, a0B, 0, 0, 0);
        a1B = __builtin_amdgcn_mfma_f32_16x16x32_bf16(afrag1, bhB, a1B, 0, 0, 0);
        // C/D: col=lane&15 (j), row=quad*4+reg (i)
        #pragma unroll
        for (int r = 0; r < 4; ++r) {
            int m0 = quad * 4 + r, m1 = m0 + 16;
            if ((a0A[r] > fmaf(0.5f, sqjA, hcut[r])) && (jA != i0 + m0)) {
                float d2 = sqi[r] + sqjA - 2.0f * a0A[r];
                int pos = atomicAdd(&cntS[m0], 1);
                if (pos < CAP) keyS[m0 * CAP + pos] = (map_f32(d2) & 0xFFFF0000u) | (unsigned)jA;
            }
            if ((a1A[r] > fmaf(0.5f, sqjA, hcut[4+r])) && (jA != i0 + m1)) {
                float d2 = sqi[4+r] + sqjA - 2.0f * a1A[r];
                int pos = atomicAdd(&cntS[m1], 1);
                if (pos < CAP) keyS[m1 * CAP + pos] = (map_f32(d2) & 0xFFFF0000u) | (unsigned)jA;
            }
            if ((a0B[r] > fmaf(0.5f, sqjB, hcut[r])) && (jB != i0 + m0)) {
                float d2 = sqi[r] + sqjB - 2.0f * a0B[r];
                int pos = atomicAdd(&cntS[m0], 1);
                if (pos < CAP) keyS[m0 * CAP + pos] = (map_f32(d2) & 0xFFFF0000u) | (unsigned)jB;
            }
            if ((a1B[r] > fmaf(0.5f, sqjB, hcut[4+r])) && (jB != i0 + m1)) {
                float d2 = sqi[4+r] + sqjB - 2.0f * a1B[r];
                int pos = atomicAdd(&cntS[m1], 1);
                if (pos < CAP) keyS[m1 * CAP + pos] = (map_f32(d2) & 0xFFFF0000u) | (unsigned)jB;
            }
        }
    }
    __syncthreads();

    // ---- phase 2: per wave, 4 rows: bisection select + ballot-prefix collect -> global (padded)
    unsigned long long ltm = (1ull << lane) - 1ull;
    for (int rr = 0; rr < 4; ++rr) {
        int m  = wave * 4 + rr;
        int pt = i0 + m;
        int C = cntS[m]; C = C < CAP ? C : CAP;
        unsigned kl[MAXL];
        #pragma unroll
        for (int tt = 0; tt < MAXL; ++tt) {
            int c = tt * 64 + lane;
            kl[tt] = (c < C) ? keyS[m * CAP + c] : 0xFFFFFFFFu;
        }
        unsigned lo = 0, hi = 0xFFFFFFFEu;
        for (int it = 0; it < 32 && lo < hi; ++it) {
            unsigned mid = lo + ((hi - lo) >> 1);
            unsigned cc = 0;
            #pragma unroll
            for (int tt = 0; tt < MAXL; ++tt)
                cc += (unsigned)__builtin_popcountll(__ballot(kl[tt] <= mid));
            if (cc >= K_NBR) hi = mid; else lo = mid + 1;
        }
        unsigned T25 = hi;

        int base = 0;
        #pragma unroll
        for (int tt = 0; tt < MAXL; ++tt) {
            bool c = kl[tt] <= T25;
            unsigned long long mk = __ballot(c);
            if (c) {
                int pos = base + __builtin_popcountll(mk & ltm);
                if (pos < K_NBR) nbrW[m][pos] = (int)(kl[tt] & 0xFFFFu);
            }
            base += __builtin_popcountll(mk);
        }
        // pad (same wave wrote nbrW -> lgkm ordering, no barrier needed)
        if (lane == 0) {
            int got = base < K_NBR ? base : K_NBR;
            int pad = (got > 0) ? nbrW[m][0] : pt;
            for (int q = got; q < K_NBR; ++q) nbrW[m][q] = pad;
        }
        if (lane < K_NBR) nbrG[(size_t)pt * K_NBR + lane] = (unsigned)nbrW[m][lane];
    }
}

// ---------------------------------------------------------------- eig + dot: 4 rows/block, grid 4096
__global__ __launch_bounds__(256) void eig_kernel(const float4* __restrict__ latv,
                                                  const float4* __restrict__ rawv,
                                                  const unsigned* __restrict__ nbrG,
                                                  float* __restrict__ accum) {
    __shared__ float ZXS[4][800];   // per wave: 400 Z + 400 X (12.8 KB)

    int wave = threadIdx.x >> 6;
    int lane = threadIdx.x & 63;
    int pt   = blockIdx.x * 4 + wave;

    float* ZS = ZXS[wave];
    float* XS = ZS + 400;

    if (lane < K_NBR) {
        int n = (int)nbrG[(size_t)pt * K_NBR + lane];
        float4* z = (float4*)&ZS[lane * D_DIM];
        float4* x = (float4*)&XS[lane * D_DIM];
        z[0] = latv[n*4+0]; z[1] = latv[n*4+1]; z[2] = latv[n*4+2]; z[3] = latv[n*4+3];
        x[0] = rawv[n*4+0]; x[1] = rawv[n*4+1]; x[2] = rawv[n*4+2]; x[3] = rawv[n*4+3];
    }
    __syncthreads();

    // 4 groups of 16 lanes: (Z,X) x (half0, half1)
    int a     = lane & 15;
    int com   = lane & 16;
    int hb    = lane >> 5;
    int sbase = lane & 48;
    float* M = com ? XS : ZS;

    int k0 = hb ? 13 : 0;
    int k1 = hb ? 25 : 13;
    {
        float s = 0.0f;
        for (int k = k0; k < k1; ++k) s += M[k * D_DIM + a];
        s += __shfl_xor(s, 32, 64);
        float mean = s * 0.04f;
        for (int k = k0; k < k1; ++k) M[k * D_DIM + a] -= mean;
    }
    __syncthreads();

    float row[16];
    #pragma unroll
    for (int b = 0; b < 16; ++b) row[b] = 0.0f;
    for (int k = k0; k < k1; ++k) {
        float va = M[k * D_DIM + a];
        #pragma unroll
        for (int b = 0; b < 16; ++b) row[b] = fmaf(va, M[k * D_DIM + b], row[b]);
    }
    #pragma unroll
    for (int b = 0; b < 16; ++b) row[b] += __shfl_xor(row[b], 32, 64);

    float mm = 1e-30f;
    #pragma unroll
    for (int b = 0; b < 16; ++b) mm = fmaxf(mm, fabsf(row[b]));
    #pragma unroll
    for (int off = 1; off < 16; off <<= 1) mm = fmaxf(mm, __shfl_xor(mm, off, 64));
    float inv = 1.0f / mm;
    #pragma unroll
    for (int b = 0; b < 16; ++b) row[b] *= inv;

    int bbase = sbase + (hb << 3);

    for (int sq2 = 0; sq2 < 2; ++sq2) {   // net C^4
        float rh[8];
        #pragma unroll
        for (int bi = 0; bi < 8; ++bi) rh[bi] = hb ? row[8 + bi] : row[bi];
        float nr[16];
        #pragma unroll
        for (int c = 0; c < 16; ++c) nr[c] = 0.0f;
        #pragma unroll
        for (int bi = 0; bi < 8; ++bi) {
            float coef = rh[bi];
            #pragma unroll
            for (int c = 0; c < 16; ++c)
                nr[c] = fmaf(coef, __shfl(row[c], bbase + bi, 64), nr[c]);
        }
        #pragma unroll
        for (int c = 0; c < 16; ++c) nr[c] += __shfl_xor(nr[c], 32, 64);
        mm = 1e-30f;
        #pragma unroll
        for (int c = 0; c < 16; ++c) mm = fmaxf(mm, fabsf(nr[c]));
        #pragma unroll
        for (int off = 1; off < 16; off <<= 1) mm = fmaxf(mm, __shfl_xor(mm, off, 64));
        inv = 1.0f / mm;
        #pragma unroll
        for (int c = 0; c < 16; ++c) row[c] = nr[c] * inv;
    }

    float rh[8];
    #pragma unroll
    for (int bi = 0; bi < 8; ++bi) rh[bi] = hb ? row[8 + bi] : row[bi];
    float v = 1.0f + 0.0625f * (float)a;
    for (int it = 0; it < 12; ++it) {     // ~C^48 effective
        float w = 0.0f;
        #pragma unroll
        for (int bi = 0; bi < 8; ++bi)
            w = fmaf(rh[bi], __shfl(v, bbase + bi, 64), w);
        w += __shfl_xor(w, 32, 64);
        float n2 = w * w;
        #pragma unroll
        for (int off = 1; off < 16; off <<= 1) n2 += __shfl_xor(n2, off, 64);
        v = w * rsqrtf(n2 + 1e-37f);
    }
    {
        float n2 = v * v;
        #pragma unroll
        for (int off = 1; off < 16; off <<= 1) n2 += __shfl_xor(n2, off, 64);
        v = v / sqrtf(n2 + 1e-37f);
    }

    float p = v * __shfl_xor(v, 16, 64);
    #pragma unroll
    for (int off = 1; off < 16; off <<= 1) p += __shfl_xor(p, off, 64);
    if (lane == 0) atomicAdd(&accum[1], p * p);
}

// ---------------------------------------------------------------- combine
__global__ void final_kernel(const float* __restrict__ accum, float* __restrict__ out) {
    float recon = accum[0] * (1.0f / (float)(B_N * D_DIM));
    float tsa   = 2.0f - 2.0f * (accum[1] * (1.0f / (float)B_N));
    out[0] = recon + 0.1f * tsa;
}

extern "C" void kernel_launch(void* const* d_in, const int* in_sizes, int n_in,
                              void* d_out, int out_size, void* d_ws, size_t ws_size,
                              hipStream_t stream) {
    const float* outputs = (const float*)d_in[0];
    const float* targets = (const float*)d_in[1];
    const float* latent  = (const float*)d_in[2];
    const float* raw     = (const float*)d_in[3];

    float* accum         = (float*)d_ws;
    float* sq            = (float*)((char*)d_ws + WS_SQ_OFF);
    float* T             = (float*)((char*)d_ws + WS_T_OFF);
    unsigned short* rawh = (unsigned short*)((char*)d_ws + WS_RAWH_OFF);
    unsigned short* rawl = (unsigned short*)((char*)d_ws + WS_RAWL_OFF);
    unsigned* nbrG       = (unsigned*)((char*)d_ws + WS_NBR_OFF);

    const float4* rawv = (const float4*)raw;
    const float4* latv = (const float4*)latent;

    hipMemsetAsync(d_ws, 0, 256, stream);  // zero accum
    prep_kernel<<<B_N / 256, 256, 0, stream>>>(rawv, (const float4*)outputs,
                                               (const float4*)targets, sq, rawh, rawl, accum);
    thresh_kernel<<<B_N / 16, 256, 0, stream>>>(rawv, rawh, sq, T);
    scan_kernel<<<B_N / 32, 512, 0, stream>>>(rawh, rawl, sq, T, nbrG);
    eig_kernel<<<B_N / 4, 256, 0, stream>>>(latv, rawv, nbrG, accum);
    final_kernel<<<1, 1, 0, stream>>>(accum, (float*)d_out);
}

// Round 11
// 425.188 us; speedup vs baseline: 1.2578x; 1.0323x over previous
//
#include <hip/hip_runtime.h>
#include <cstdint>
#include <cstddef>

// Problem constants
#define B_N   16384
#define D_DIM 16
#define K_NBR 25
#define CAP   256       // per-row LDS candidate capacity (E[C]~96)
#define MAXL  4         // CAP/64
#define NSAMP 1024      // threshold sample count per row
#define EPAD  20        // u16 row pad for eig M staging (40 B rows, b64-aligned)
#define CPAD  20        // f32 row pad for eig C buffer (80 B rows, b128-aligned)

// Workspace: accum | sq | T | rawh | rawl | lath | latl | nbrG
#define WS_SQ_OFF   256
#define WS_T_OFF    (WS_SQ_OFF + 65536)
#define WS_RAWH_OFF (WS_T_OFF + 65536)
#define WS_RAWL_OFF (WS_RAWH_OFF + B_N * D_DIM * 2)
#define WS_LATH_OFF (WS_RAWL_OFF + B_N * D_DIM * 2)
#define WS_LATL_OFF (WS_LATH_OFF + B_N * D_DIM * 2)
#define WS_NBR_OFF  (WS_LATL_OFF + B_N * D_DIM * 2)

typedef __attribute__((ext_vector_type(8))) short bf16x8;
typedef __attribute__((ext_vector_type(4))) float f32x4;

__device__ __forceinline__ unsigned map_f32(float x) {
    unsigned u = __float_as_uint(x);
    return (u & 0x80000000u) ? ~u : (u | 0x80000000u); // order-preserving
}

__device__ __forceinline__ unsigned short f2bf(float x) {   // RNE f32->bf16 bits
    unsigned u = __float_as_uint(x);
    unsigned r = (u + 0x7FFFu + ((u >> 16) & 1u)) >> 16;
    return (unsigned short)r;
}
__device__ __forceinline__ float bf2f(unsigned short h) {
    return __uint_as_float(((unsigned)h) << 16);
}

// ---------------------------------------------------------------- prep: sq + recon + bf16 hi/lo splits
__global__ __launch_bounds__(256) void prep_kernel(const float4* __restrict__ rawv,
                                                   const float4* __restrict__ latv,
                                                   const float4* __restrict__ ov,
                                                   const float4* __restrict__ tv,
                                                   float* __restrict__ sq,
                                                   unsigned short* __restrict__ rawh,
                                                   unsigned short* __restrict__ rawl,
                                                   unsigned short* __restrict__ lath,
                                                   unsigned short* __restrict__ latl,
                                                   float* __restrict__ accum) {
    int i = blockIdx.x * 256 + threadIdx.x;
    float v[16];
    {
        float4 r0 = rawv[i*4+0], r1 = rawv[i*4+1], r2 = rawv[i*4+2], r3 = rawv[i*4+3];
        v[0]=r0.x; v[1]=r0.y; v[2]=r0.z; v[3]=r0.w;
        v[4]=r1.x; v[5]=r1.y; v[6]=r1.z; v[7]=r1.w;
        v[8]=r2.x; v[9]=r2.y; v[10]=r2.z; v[11]=r2.w;
        v[12]=r3.x; v[13]=r3.y; v[14]=r3.z; v[15]=r3.w;
    }
    float s = 0.0f;
    unsigned short h[16], l[16];
    #pragma unroll
    for (int k = 0; k < 16; ++k) {
        s = fmaf(v[k], v[k], s);
        unsigned short hh = f2bf(v[k]);
        h[k] = hh;
        l[k] = f2bf(v[k] - bf2f(hh));
    }
    sq[i] = s;
    #pragma unroll
    for (int q = 0; q < 4; ++q) {
        ((ushort4*)(rawh + (size_t)i*16))[q] = make_ushort4(h[q*4], h[q*4+1], h[q*4+2], h[q*4+3]);
        ((ushort4*)(rawl + (size_t)i*16))[q] = make_ushort4(l[q*4], l[q*4+1], l[q*4+2], l[q*4+3]);
    }
    // latent split
    {
        float4 r0 = latv[i*4+0], r1 = latv[i*4+1], r2 = latv[i*4+2], r3 = latv[i*4+3];
        v[0]=r0.x; v[1]=r0.y; v[2]=r0.z; v[3]=r0.w;
        v[4]=r1.x; v[5]=r1.y; v[6]=r1.z; v[7]=r1.w;
        v[8]=r2.x; v[9]=r2.y; v[10]=r2.z; v[11]=r2.w;
        v[12]=r3.x; v[13]=r3.y; v[14]=r3.z; v[15]=r3.w;
        #pragma unroll
        for (int k = 0; k < 16; ++k) {
            unsigned short hh = f2bf(v[k]);
            h[k] = hh;
            l[k] = f2bf(v[k] - bf2f(hh));
        }
        #pragma unroll
        for (int q = 0; q < 4; ++q) {
            ((ushort4*)(lath + (size_t)i*16))[q] = make_ushort4(h[q*4], h[q*4+1], h[q*4+2], h[q*4+3]);
            ((ushort4*)(latl + (size_t)i*16))[q] = make_ushort4(l[q*4], l[q*4+1], l[q*4+2], l[q*4+3]);
        }
    }

    float rs = 0.0f;
    #pragma unroll
    for (int q = 0; q < 4; ++q) {
        float4 o = ov[i*4+q], t = tv[i*4+q];
        float d;
        d = o.x - t.x; rs = fmaf(d, d, rs);
        d = o.y - t.y; rs = fmaf(d, d, rs);
        d = o.z - t.z; rs = fmaf(d, d, rs);
        d = o.w - t.w; rs = fmaf(d, d, rs);
    }
    #pragma unroll
    for (int off = 32; off >= 1; off >>= 1) rs += __shfl_down(rs, off, 64);
    if ((threadIdx.x & 63) == 0) atomicAdd(&accum[0], rs);
}

// ---------------------------------------------------------------- per-row distance threshold, LDS-staged
__global__ __launch_bounds__(256) void thresh_kernel(const float4* __restrict__ rawv,
                                                     const unsigned short* __restrict__ rawh,
                                                     const float* __restrict__ sq,
                                                     float* __restrict__ T) {
    __shared__ unsigned short sampH[NSAMP * 16];
    __shared__ float sampSq[NSAMP];
    __shared__ float V[16][48];

    int tid = threadIdx.x;
    for (int s = tid; s < NSAMP; s += 256) {
        int js = s << 4;
        const uint4* src = (const uint4*)(rawh + (size_t)js * 16);
        ((uint4*)(sampH + s * 16))[0] = src[0];
        ((uint4*)(sampH + s * 16))[1] = src[1];
        sampSq[s] = sq[js];
    }

    int rl   = tid >> 4;
    int sidx = tid & 15;
    int i = blockIdx.x * 16 + rl;

    float a[16];
    {
        float4 r0 = rawv[i*4+0], r1 = rawv[i*4+1], r2 = rawv[i*4+2], r3 = rawv[i*4+3];
        a[0]=r0.x; a[1]=r0.y; a[2]=r0.z; a[3]=r0.w;
        a[4]=r1.x; a[5]=r1.y; a[6]=r1.z; a[7]=r1.w;
        a[8]=r2.x; a[9]=r2.y; a[10]=r2.z; a[11]=r2.w;
        a[12]=r3.x; a[13]=r3.y; a[14]=r3.z; a[15]=r3.w;
    }
    float sqi = sq[i];
    __syncthreads();

    float s0 = 3e37f, s1 = 3e37f, s2 = 3e37f;
    for (int t = 0; t < NSAMP / 16; ++t) {
        int s = t * 16 + sidx;
        const uint4* bp = (const uint4*)(sampH + s * 16);
        uint4 h0 = bp[0], h1 = bp[1];
        float dot = 0.0f;
        unsigned w;
        w = h0.x; dot = fmaf(a[0],  __uint_as_float(w << 16), dot); dot = fmaf(a[1],  __uint_as_float(w & 0xFFFF0000u), dot);
        w = h0.y; dot = fmaf(a[2],  __uint_as_float(w << 16), dot); dot = fmaf(a[3],  __uint_as_float(w & 0xFFFF0000u), dot);
        w = h0.z; dot = fmaf(a[4],  __uint_as_float(w << 16), dot); dot = fmaf(a[5],  __uint_as_float(w & 0xFFFF0000u), dot);
        w = h0.w; dot = fmaf(a[6],  __uint_as_float(w << 16), dot); dot = fmaf(a[7],  __uint_as_float(w & 0xFFFF0000u), dot);
        w = h1.x; dot = fmaf(a[8],  __uint_as_float(w << 16), dot); dot = fmaf(a[9],  __uint_as_float(w & 0xFFFF0000u), dot);
        w = h1.y; dot = fmaf(a[10], __uint_as_float(w << 16), dot); dot = fmaf(a[11], __uint_as_float(w & 0xFFFF0000u), dot);
        w = h1.z; dot = fmaf(a[12], __uint_as_float(w << 16), dot); dot = fmaf(a[13], __uint_as_float(w & 0xFFFF0000u), dot);
        w = h1.w; dot = fmaf(a[14], __uint_as_float(w << 16), dot); dot = fmaf(a[15], __uint_as_float(w & 0xFFFF0000u), dot);
        float cur = sqi + sampSq[s] - 2.0f * dot;
        float lo;
        lo = fminf(s0, cur); cur = fmaxf(s0, cur); s0 = lo;
        lo = fminf(s1, cur); cur = fmaxf(s1, cur); s1 = lo;
        lo = fminf(s2, cur); cur = fmaxf(s2, cur); s2 = lo;
    }

    V[rl][sidx*3+0] = s0; V[rl][sidx*3+1] = s1; V[rl][sidx*3+2] = s2;
    __syncthreads();

    int cl0 = 0, cq0 = 0, cl1 = 0, cq1 = 0, cl2 = 0, cq2 = 0;
    for (int k = 0; k < 48; ++k) {
        float v = V[rl][k];
        cl0 += (v < s0); cq0 += (v <= s0);
        cl1 += (v < s1); cq1 += (v <= s1);
        cl2 += (v < s2); cq2 += (v <= s2);
    }
    if (cl0 <= 5 && 5 < cq0) T[i] = s0 + 0.05f;
    else if (cl1 <= 5 && 5 < cq1) T[i] = s1 + 0.05f;
    else if (cl2 <= 5 && 5 < cq2) T[i] = s2 + 0.05f;
}

// ---------------------------------------------------------------- MFMA scan + select: 32 rows/block, 512 thr
// NOTE: plain __launch_bounds__ only — (256,4) caused a 64-VGPR cap + unified-AGPR split and
// massive scratch spill on gfx950 (R7/R8, 183 MB writes). Do not add the second argument.
__global__ __launch_bounds__(512) void scan_kernel(const unsigned short* __restrict__ rawh,
                                                   const unsigned short* __restrict__ rawl,
                                                   const float* __restrict__ sq,
                                                   const float* __restrict__ T,
                                                   unsigned* __restrict__ nbrG) {
    __shared__ unsigned keyS[32 * CAP];
    __shared__ int      cntS[32];
    __shared__ int      nbrW[32][K_NBR];

    int tid  = threadIdx.x;
    int wave = tid >> 6;
    int lane = tid & 63;
    int quad = lane >> 4;
    int lnib = lane & 15;
    int i0   = blockIdx.x * 32;
    int koff = (quad & 1) * 8;

    if (tid < 32) cntS[tid] = 0;

    const unsigned short* ab = (quad < 2 ? rawh : rawl) + (size_t)(i0 + lnib) * 16 + koff;
    bf16x8 afrag0 = *(const bf16x8*)ab;
    bf16x8 afrag1 = *(const bf16x8*)(ab + 16 * 16);

    float sqi[8], hcut[8];
    #pragma unroll
    for (int r = 0; r < 4; ++r) {
        int m = quad * 4 + r;
        sqi[r]     = sq[i0 + m];
        hcut[r]    = 0.5f * (sqi[r] - T[i0 + m]);
        sqi[4+r]   = sq[i0 + m + 16];
        hcut[4+r]  = 0.5f * (sqi[4+r] - T[i0 + m + 16]);
    }
    __syncthreads();

    for (int t = wave; t < B_N / 16; t += 16) {
        int jA = t * 16 + lnib;
        int jB = jA + 128;
        bf16x8 bhA = *(const bf16x8*)(rawh + (size_t)jA * 16 + koff);
        bf16x8 blA = *(const bf16x8*)(rawl + (size_t)jA * 16 + koff);
        bf16x8 bhB = *(const bf16x8*)(rawh + (size_t)jB * 16 + koff);
        bf16x8 blB = *(const bf16x8*)(rawl + (size_t)jB * 16 + koff);
        float sqjA = sq[jA];
        float sqjB = sq[jB];
        f32x4 a0A = {0,0,0,0}, a1A = {0,0,0,0}, a0B = {0,0,0,0}, a1B = {0,0,0,0};
        a0A = __builtin_amdgcn_mfma_f32_16x16x32_bf16(afrag0, blA, a0A, 0, 0, 0);
        a1A = __builtin_amdgcn_mfma_f32_16x16x32_bf16(afrag1, blA, a1A, 0, 0, 0);
        a0B = __builtin_amdgcn_mfma_f32_16x16x32_bf16(afrag0, blB, a0B, 0, 0, 0);
        a1B = __builtin_amdgcn_mfma_f32_16x16x32_bf16(afrag1, blB, a1B, 0, 0, 0);
        a0A = __builtin_amdgcn_mfma_f32_16x16x32_bf16(afrag0, bhA, a0A, 0, 0, 0);
        a1A = __builtin_amdgcn_mfma_f32_16x16x32_bf16(afrag1, bhA, a1A, 0, 0, 0);
        a0B = __builtin_amdgcn_mfma_f32_16x16x32_bf16(afrag0, bhB, a0B, 0, 0, 0);
        a1B = __builtin_amdgcn_mfma_f32_16x16x32_bf16(afrag1, bhB, a1B, 0, 0, 0);
        #pragma unroll
        for (int r = 0; r < 4; ++r) {
            int m0 = quad * 4 + r, m1 = m0 + 16;
            if ((a0A[r] > fmaf(0.5f, sqjA, hcut[r])) && (jA != i0 + m0)) {
                float d2 = sqi[r] + sqjA - 2.0f * a0A[r];
                int pos = atomicAdd(&cntS[m0], 1);
                if (pos < CAP) keyS[m0 * CAP + pos] = (map_f32(d2) & 0xFFFF0000u) | (unsigned)jA;
            }
            if ((a1A[r] > fmaf(0.5f, sqjA, hcut[4+r])) && (jA != i0 + m1)) {
                float d2 = sqi[4+r] + sqjA - 2.0f * a1A[r];
                int pos = atomicAdd(&cntS[m1], 1);
                if (pos < CAP) keyS[m1 * CAP + pos] = (map_f32(d2) & 0xFFFF0000u) | (unsigned)jA;
            }
            if ((a0B[r] > fmaf(0.5f, sqjB, hcut[r])) && (jB != i0 + m0)) {
                float d2 = sqi[r] + sqjB - 2.0f * a0B[r];
                int pos = atomicAdd(&cntS[m0], 1);
                if (pos < CAP) keyS[m0 * CAP + pos] = (map_f32(d2) & 0xFFFF0000u) | (unsigned)jB;
            }
            if ((a1B[r] > fmaf(0.5f, sqjB, hcut[4+r])) && (jB != i0 + m1)) {
                float d2 = sqi[4+r] + sqjB - 2.0f * a1B[r];
                int pos = atomicAdd(&cntS[m1], 1);
                if (pos < CAP) keyS[m1 * CAP + pos] = (map_f32(d2) & 0xFFFF0000u) | (unsigned)jB;
            }
        }
    }
    __syncthreads();

    unsigned long long ltm = (1ull << lane) - 1ull;
    for (int rr = 0; rr < 4; ++rr) {
        int m  = wave * 4 + rr;
        int pt = i0 + m;
        int C = cntS[m]; C = C < CAP ? C : CAP;
        unsigned kl[MAXL];
        #pragma unroll
        for (int tt = 0; tt < MAXL; ++tt) {
            int c = tt * 64 + lane;
            kl[tt] = (c < C) ? keyS[m * CAP + c] : 0xFFFFFFFFu;
        }
        unsigned lo = 0, hi = 0xFFFFFFFEu;
        for (int it = 0; it < 32 && lo < hi; ++it) {
            unsigned mid = lo + ((hi - lo) >> 1);
            unsigned cc = 0;
            #pragma unroll
            for (int tt = 0; tt < MAXL; ++tt)
                cc += (unsigned)__builtin_popcountll(__ballot(kl[tt] <= mid));
            if (cc >= K_NBR) hi = mid; else lo = mid + 1;
        }
        unsigned T25 = hi;

        int base = 0;
        #pragma unroll
        for (int tt = 0; tt < MAXL; ++tt) {
            bool c = kl[tt] <= T25;
            unsigned long long mk = __ballot(c);
            if (c) {
                int pos = base + __builtin_popcountll(mk & ltm);
                if (pos < K_NBR) nbrW[m][pos] = (int)(kl[tt] & 0xFFFFu);
            }
            base += __builtin_popcountll(mk);
        }
        if (lane == 0) {
            int got = base < K_NBR ? base : K_NBR;
            int pad = (got > 0) ? nbrW[m][0] : pt;
            for (int q = got; q < K_NBR; ++q) nbrW[m][q] = pad;
        }
        if (lane < K_NBR) nbrG[(size_t)pt * K_NBR + lane] = (unsigned)nbrW[m][lane];
    }
}

// ---------------------------------------------------------------- eig v3: MFMA trace method
// (u.v)^2 = tr(Az*Ax) with A = trace-normalized C^32.
// Cov = M^T M - colsum x colsum /25 via MFMA (col-read frags, A==B content; ones-vector
// MFMAs for colsums). Squarings: C-frag -> LDS -> bf16 hi/lo frags -> 3 MFMA -> renorm.
// One point per wave; no big per-lane arrays (max live = 4-reg acc frags) -> no scratch.
__global__ __launch_bounds__(256) void eig_kernel(const unsigned short* __restrict__ lath,
                                                  const unsigned short* __restrict__ latl,
                                                  const unsigned short* __restrict__ rawh,
                                                  const unsigned short* __restrict__ rawl,
                                                  const unsigned* __restrict__ nbrG,
                                                  float* __restrict__ accum) {
    __shared__ unsigned short MS[4][2][2][32 * EPAD];  // [wave][comm][h/l] 25 rows + 7 zero rows
    __shared__ float CS[4][2][16 * CPAD];              // C round-trip buffers

    int wave = threadIdx.x >> 6;
    int lane = threadIdx.x & 63;
    int quad = lane >> 4;
    int lnib = lane & 15;
    int pt   = blockIdx.x * 4 + wave;

    // ---- stage: lane -> (comm = lane>>5, row = lane&31); rows 25..31 zeroed
    {
        int comm = lane >> 5;
        int row  = lane & 31;
        uint2* dh = (uint2*)&MS[wave][comm][0][row * EPAD];
        uint2* dl = (uint2*)&MS[wave][comm][1][row * EPAD];
        if (row < K_NBR) {
            int n = (int)nbrG[(size_t)pt * K_NBR + row];
            const uint2* sh = (const uint2*)((comm ? rawh : lath) + (size_t)n * 16);
            const uint2* sl = (const uint2*)((comm ? rawl : latl) + (size_t)n * 16);
            dh[0] = sh[0]; dh[1] = sh[1]; dh[2] = sh[2]; dh[3] = sh[3];
            dl[0] = sl[0]; dl[1] = sl[1]; dl[2] = sl[2]; dl[3] = sl[3];
        } else {
            uint2 z = make_uint2(0u, 0u);
            dh[0] = z; dh[1] = z; dh[2] = z; dh[3] = z;
            dl[0] = z; dl[1] = z; dl[2] = z; dl[3] = z;
        }
    }
    __syncthreads();

    bf16x8 ones;
    #pragma unroll
    for (int j = 0; j < 8; ++j) ones[j] = (short)0x3F80;

    float az0[4];   // saved comm-0 (latent) result
    f32x4 az;

    for (int comm = 0; comm < 2; ++comm) {
        const unsigned short* Mh = &MS[wave][comm][0][0];
        const unsigned short* Ml = &MS[wave][comm][1][0];

        // column-read frags: lane holds M[k][lnib], k = quad*8+j  (A-content == B-content)
        bf16x8 fh, fl;
        #pragma unroll
        for (int j = 0; j < 8; ++j) {
            int k = quad * 8 + j;
            fh[j] = (short)Mh[k * EPAD + lnib];
            fl[j] = (short)Ml[k * EPAD + lnib];
        }

        // M^T M (hh + hl + lh)
        f32x4 mtm = {0.f, 0.f, 0.f, 0.f};
        mtm = __builtin_amdgcn_mfma_f32_16x16x32_bf16(fh, fh, mtm, 0, 0, 0);
        mtm = __builtin_amdgcn_mfma_f32_16x16x32_bf16(fh, fl, mtm, 0, 0, 0);
        mtm = __builtin_amdgcn_mfma_f32_16x16x32_bf16(fl, fh, mtm, 0, 0, 0);
        // colsum by row index (D1[m][n] = colsum[m]) and by col index (D2[m][n] = colsum[n])
        f32x4 d1 = {0.f, 0.f, 0.f, 0.f};
        d1 = __builtin_amdgcn_mfma_f32_16x16x32_bf16(fh, ones, d1, 0, 0, 0);
        d1 = __builtin_amdgcn_mfma_f32_16x16x32_bf16(fl, ones, d1, 0, 0, 0);
        f32x4 d2 = {0.f, 0.f, 0.f, 0.f};
        d2 = __builtin_amdgcn_mfma_f32_16x16x32_bf16(ones, fh, d2, 0, 0, 0);
        d2 = __builtin_amdgcn_mfma_f32_16x16x32_bf16(ones, fl, d2, 0, 0, 0);

        // Cov (C-frag: col=lnib, row=quad*4+r), then trace-normalize
        #pragma unroll
        for (int r = 0; r < 4; ++r) az[r] = mtm[r] - d1[r] * d2[r] * 0.04f;
        {
            float tl = (quad == (lnib >> 2)) ? az[lnib & 3] : 0.0f;
            #pragma unroll
            for (int off = 1; off < 64; off <<= 1) tl += __shfl_xor(tl, off, 64);
            float inv = 1.0f / tl;
            #pragma unroll
            for (int r = 0; r < 4; ++r) az[r] *= inv;
        }

        // 5 squarings: C^32 (symmetric throughout -> row-read == col-read)
        float* C = &CS[wave][comm][0];
        for (int s = 0; s < 5; ++s) {
            #pragma unroll
            for (int r = 0; r < 4; ++r) C[(quad * 4 + r) * CPAD + lnib] = az[r];
            // read row lnib, elements quad*8..quad*8+7 (intra-wave LDS ordering; same-array alias keeps order)
            f32x4 c0 = *(const f32x4*)&C[lnib * CPAD + quad * 8];
            f32x4 c1 = *(const f32x4*)&C[lnib * CPAD + quad * 8 + 4];
            float vals[8] = {c0[0], c0[1], c0[2], c0[3], c1[0], c1[1], c1[2], c1[3]};
            bf16x8 gh, gl;
            #pragma unroll
            for (int e = 0; e < 8; ++e) {
                unsigned short hh = f2bf(vals[e]);
                gh[e] = (short)hh;
                gl[e] = (short)f2bf(vals[e] - bf2f(hh));
            }
            f32x4 nz = {0.f, 0.f, 0.f, 0.f};
            nz = __builtin_amdgcn_mfma_f32_16x16x32_bf16(gh, gh, nz, 0, 0, 0);
            nz = __builtin_amdgcn_mfma_f32_16x16x32_bf16(gh, gl, nz, 0, 0, 0);
            nz = __builtin_amdgcn_mfma_f32_16x16x32_bf16(gl, gh, nz, 0, 0, 0);
            float tl = (quad == (lnib >> 2)) ? nz[lnib & 3] : 0.0f;
            #pragma unroll
            for (int off = 1; off < 64; off <<= 1) tl += __shfl_xor(tl, off, 64);
            float inv = 1.0f / tl;
            #pragma unroll
            for (int r = 0; r < 4; ++r) az[r] = nz[r] * inv;
        }

        if (comm == 0) {
            #pragma unroll
            for (int r = 0; r < 4; ++r) az0[r] = az[r];
        }
    }

    // p^2 = tr(Az*Ax) = elementwise dot (both trace-normalized, symmetric)
    float pl = az0[0]*az[0] + az0[1]*az[1] + az0[2]*az[2] + az0[3]*az[3];
    #pragma unroll
    for (int off = 1; off < 64; off <<= 1) pl += __shfl_xor(pl, off, 64);
    if (lane == 0) atomicAdd(&accum[1], pl);
}

// ---------------------------------------------------------------- combine
__global__ void final_kernel(const float* __restrict__ accum, float* __restrict__ out) {
    float recon = accum[0] * (1.0f / (float)(B_N * D_DIM));
    float tsa   = 2.0f - 2.0f * (accum[1] * (1.0f / (float)B_N));
    out[0] = recon + 0.1f * tsa;
}

extern "C" void kernel_launch(void* const* d_in, const int* in_sizes, int n_in,
                              void* d_out, int out_size, void* d_ws, size_t ws_size,
                              hipStream_t stream) {
    const float* outputs = (const float*)d_in[0];
    const float* targets = (const float*)d_in[1];
    const float* latent  = (const float*)d_in[2];
    const float* raw     = (const float*)d_in[3];

    float* accum         = (float*)d_ws;
    float* sq            = (float*)((char*)d_ws + WS_SQ_OFF);
    float* T             = (float*)((char*)d_ws + WS_T_OFF);
    unsigned short* rawh = (unsigned short*)((char*)d_ws + WS_RAWH_OFF);
    unsigned short* rawl = (unsigned short*)((char*)d_ws + WS_RAWL_OFF);
    unsigned short* lath = (unsigned short*)((char*)d_ws + WS_LATH_OFF);
    unsigned short* latl = (unsigned short*)((char*)d_ws + WS_LATL_OFF);
    unsigned* nbrG       = (unsigned*)((char*)d_ws + WS_NBR_OFF);

    const float4* rawv = (const float4*)raw;
    const float4* latv = (const float4*)latent;

    hipMemsetAsync(d_ws, 0, 256, stream);  // zero accum
    prep_kernel<<<B_N / 256, 256, 0, stream>>>(rawv, latv, (const float4*)outputs,
                                               (const float4*)targets, sq, rawh, rawl,
                                               lath, latl, accum);
    thresh_kernel<<<B_N / 16, 256, 0, stream>>>(rawv, rawh, sq, T);
    scan_kernel<<<B_N / 32, 512, 0, stream>>>(rawh, rawl, sq, T, nbrG);
    eig_kernel<<<B_N / 4, 256, 0, stream>>>(lath, latl, rawh, rawl, nbrG, accum);
    final_kernel<<<1, 1, 0, stream>>>(accum, (float*)d_out);
}